// Round 8
// baseline (78.608 us; speedup 1.0000x reference)
//
#include <hip/hip_runtime.h>
#include <math.h>

#define BB 128   // batch
#define VV 4     // views
#define NN 512   // BB*VV rows
#define DD 128   // feature dim
#define NT 256   // threads per block
#define NBLK 256 // blocks; 2 anchors per block
#define MAGIC 0x5151FA7Eu   // != 0xAAAAAAAA ws-poison, != 0

// ---------------------------------------------------------------------------
// Single kernel, 256 blocks, 2 anchors per block (a0=bid, a1=bid+256).
// Phase 1: one fused sweep over all 512 rows computes ss_j and dot_j vs BOTH
//   anchors (8 lanes/row, 4 float4 loads/lane, butterfly reduce). Anchor
//   fragments in NAMED scalars — indexed arrays spill to scratch (R5: VGPR 32,
//   44.9 us) and cg grid.sync() does the same (R6: VGPR 24, 53 us).
// Phase 2: per anchor: d_j = sqrt(max(sn_a+sn_j-2*dot*inv_a*inv_j,0))
//   (absmax 0.0 in rounds 2-7), ballot compaction into per-anchor pos/neg
//   LDS buffers, relu pair loops -> one partial per block.
// Phase 3: device-scope partial store + fence + flag=MAGIC; block 0 polls
//   256 flags with s_sleep backoff (R7's unthrottled 512-thread spin stole
//   issue slots / saturated the coherent point -> +10 us tail), reduces,
//   writes out. Init-independent: only needs initial flag != MAGIC.
// ---------------------------------------------------------------------------
__global__ __launch_bounds__(NT)
void fused_all(const float* __restrict__ feat,
               const int* __restrict__ labels,
               float* __restrict__ psum,
               float* __restrict__ pcnt,
               unsigned int* __restrict__ flag,
               float* __restrict__ out) {
    __shared__ float s_ss[NN];
    __shared__ float s_dot[2][NN];
    __shared__ float s_pos[2][NN];
    __shared__ float s_neg[2][NN];
    __shared__ int   s_lab[BB];
    __shared__ int   s_np[2], s_nn[2];
    __shared__ float s_wsum[NT / 64];
    __shared__ unsigned int s_wcnt[NT / 64];

    const int bid  = blockIdx.x;
    const int tid  = threadIdx.x;
    const int wave = tid >> 6;      // 0..3
    const int lane = tid & 63;
    const int grp  = lane >> 3;     // 8 row-groups of 8 lanes
    const int l8   = lane & 7;

    if (tid < BB) s_lab[tid] = labels[tid];
    if (tid == 0) { s_np[0] = 0; s_nn[0] = 0; s_np[1] = 0; s_nn[1] = 0; }

    // anchor fragments for both anchors — NAMED scalars (no spill)
    const int a0 = bid, a1 = bid + NBLK;
    const float4* ar0 = (const float4*)(feat + (size_t)(a0 & (BB - 1)) * (VV * DD) + (a0 >> 7) * DD);
    const float4* ar1 = (const float4*)(feat + (size_t)(a1 & (BB - 1)) * (VV * DD) + (a1 >> 7) * DD);
    float4 af0 = ar0[l8];
    float4 af1 = ar0[l8 + 8];
    float4 af2 = ar0[l8 + 16];
    float4 af3 = ar0[l8 + 24];
    float4 bf0 = ar1[l8];
    float4 bf1 = ar1[l8 + 8];
    float4 bf2 = ar1[l8 + 16];
    float4 bf3 = ar1[l8 + 24];

    // Phase 1: fused ss + dual-dot sweep; wave w covers rows [w*128, w*128+128)
    #pragma unroll 4
    for (int it = 0; it < 16; ++it) {
        const int j  = (wave << 7) + (it << 3) + grp;
        const int jb = j & (BB - 1), jv = j >> 7;
        const float4* jr = (const float4*)(feat + (size_t)jb * (VV * DD) + jv * DD);
        float4 x0 = jr[l8];
        float4 x1 = jr[l8 + 8];
        float4 x2 = jr[l8 + 16];
        float4 x3 = jr[l8 + 24];

        float ss = 0.f, d0 = 0.f, d1 = 0.f;
        ss = fmaf(x0.x, x0.x, fmaf(x0.y, x0.y, fmaf(x0.z, x0.z, fmaf(x0.w, x0.w, ss))));
        ss = fmaf(x1.x, x1.x, fmaf(x1.y, x1.y, fmaf(x1.z, x1.z, fmaf(x1.w, x1.w, ss))));
        ss = fmaf(x2.x, x2.x, fmaf(x2.y, x2.y, fmaf(x2.z, x2.z, fmaf(x2.w, x2.w, ss))));
        ss = fmaf(x3.x, x3.x, fmaf(x3.y, x3.y, fmaf(x3.z, x3.z, fmaf(x3.w, x3.w, ss))));
        d0 = fmaf(x0.x, af0.x, fmaf(x0.y, af0.y, fmaf(x0.z, af0.z, fmaf(x0.w, af0.w, d0))));
        d0 = fmaf(x1.x, af1.x, fmaf(x1.y, af1.y, fmaf(x1.z, af1.z, fmaf(x1.w, af1.w, d0))));
        d0 = fmaf(x2.x, af2.x, fmaf(x2.y, af2.y, fmaf(x2.z, af2.z, fmaf(x2.w, af2.w, d0))));
        d0 = fmaf(x3.x, af3.x, fmaf(x3.y, af3.y, fmaf(x3.z, af3.z, fmaf(x3.w, af3.w, d0))));
        d1 = fmaf(x0.x, bf0.x, fmaf(x0.y, bf0.y, fmaf(x0.z, bf0.z, fmaf(x0.w, bf0.w, d1))));
        d1 = fmaf(x1.x, bf1.x, fmaf(x1.y, bf1.y, fmaf(x1.z, bf1.z, fmaf(x1.w, bf1.w, d1))));
        d1 = fmaf(x2.x, bf2.x, fmaf(x2.y, bf2.y, fmaf(x2.z, bf2.z, fmaf(x2.w, bf2.w, d1))));
        d1 = fmaf(x3.x, bf3.x, fmaf(x3.y, bf3.y, fmaf(x3.z, bf3.z, fmaf(x3.w, bf3.w, d1))));

        #pragma unroll
        for (int off = 4; off > 0; off >>= 1) {
            ss += __shfl_xor(ss, off);
            d0 += __shfl_xor(d0, off);
            d1 += __shfl_xor(d1, off);
        }
        if (l8 == 0) { s_ss[j] = ss; s_dot[0][j] = d0; s_dot[1][j] = d1; }
    }
    __syncthreads();

    // Phase 2a+2b: per-anchor distances + compaction into per-anchor buffers
    #pragma unroll
    for (int h = 0; h < 2; ++h) {
        const int a = bid + (h << 8);
        const float ssa  = s_ss[a];
        const float inva = 1.f / fmaxf(sqrtf(ssa), 1e-12f);
        const float sna  = ssa * inva * inva;
        const int la = s_lab[a & (BB - 1)];
        #pragma unroll
        for (int rnd = 0; rnd < 2; ++rnd) {
            const int j = tid + (rnd << 8);
            float ssj  = s_ss[j];
            float invj = 1.f / fmaxf(sqrtf(ssj), 1e-12f);
            float snj  = ssj * invj * invj;
            float dot  = s_dot[h][j] * inva * invj;
            float sq   = fmaxf(sna + snj - 2.f * dot, 0.f);
            float dj   = (sq > 0.f) ? sqrtf(sq) : 0.f;   // safe_sqrt

            bool same  = (s_lab[j & (BB - 1)] == la);
            bool ispos = same & (j != a);
            bool isneg = !same;
            unsigned long long mp = __ballot(ispos);
            unsigned long long mn = __ballot(isneg);
            int basep = 0, basen = 0;
            if (lane == 0) {
                basep = atomicAdd(&s_np[h], (int)__popcll(mp));
                basen = atomicAdd(&s_nn[h], (int)__popcll(mn));
            }
            basep = __shfl(basep, 0);
            basen = __shfl(basen, 0);
            unsigned long long below = (1ull << lane) - 1ull;
            if (ispos) s_pos[h][basep + (int)__popcll(mp & below)] = dj;
            if (isneg) s_neg[h][basen + (int)__popcll(mn & below)] = dj;
        }
    }
    __syncthreads();

    // Phase 2c: pair loops for both anchors
    float lsum = 0.f;
    unsigned int lcnt = 0;
    #pragma unroll
    for (int h = 0; h < 2; ++h) {
        const int np = s_np[h], nneg = s_nn[h];
        for (int p = 0; p < np; ++p) {
            float dp = s_pos[h][p];              // LDS broadcast
            for (int n = tid; n < nneg; n += NT) {
                float diff = dp - s_neg[h][n];
                if (diff > 0.f) { lsum += diff; lcnt++; }
            }
        }
    }

    // Phase 3: block reduce -> partial + release flag
    #pragma unroll
    for (int off = 32; off > 0; off >>= 1) {
        lsum += __shfl_down(lsum, off);
        lcnt += __shfl_down(lcnt, off);
    }
    if (lane == 0) { s_wsum[wave] = lsum; s_wcnt[wave] = lcnt; }
    __syncthreads();
    if (tid == 0) {
        float S = s_wsum[0] + s_wsum[1] + s_wsum[2] + s_wsum[3];
        float C = (float)(s_wcnt[0] + s_wcnt[1] + s_wcnt[2] + s_wcnt[3]);
        __hip_atomic_store(&psum[bid], S, __ATOMIC_RELAXED, __HIP_MEMORY_SCOPE_AGENT);
        __hip_atomic_store(&pcnt[bid], C, __ATOMIC_RELAXED, __HIP_MEMORY_SCOPE_AGENT);
        __threadfence();   // partials visible at device scope before flag
        __hip_atomic_store(&flag[bid], MAGIC, __ATOMIC_RELEASE, __HIP_MEMORY_SCOPE_AGENT);
    }

    // Block 0: throttled wait for all 256 flags, then finalize
    if (bid == 0) {
        while (__hip_atomic_load(&flag[tid], __ATOMIC_RELAXED,
                                 __HIP_MEMORY_SCOPE_AGENT) != MAGIC) {
            __builtin_amdgcn_s_sleep(2);     // ~128-cycle nap: don't hammer L2
        }
        __threadfence();   // acquire: partials ordered after flag observation
        float s = __hip_atomic_load(&psum[tid], __ATOMIC_RELAXED, __HIP_MEMORY_SCOPE_AGENT);
        float c = __hip_atomic_load(&pcnt[tid], __ATOMIC_RELAXED, __HIP_MEMORY_SCOPE_AGENT);
        #pragma unroll
        for (int off = 32; off > 0; off >>= 1) {
            s += __shfl_down(s, off);
            c += __shfl_down(c, off);
        }
        __syncthreads();   // s_wsum/s_wcnt reuse safe
        if (lane == 0) { s_wsum[wave] = s; s_wcnt[wave] = (unsigned int)c; }
        __syncthreads();
        if (tid == 0) {
            float S = s_wsum[0] + s_wsum[1] + s_wsum[2] + s_wsum[3];
            float C = (float)(s_wcnt[0] + s_wcnt[1] + s_wcnt[2] + s_wcnt[3]);
            out[0] = (C > 0.f) ? S / C : 0.f;
        }
    }
}

extern "C" void kernel_launch(void* const* d_in, const int* in_sizes, int n_in,
                              void* d_out, int out_size, void* d_ws, size_t ws_size,
                              hipStream_t stream) {
    const float* feat   = (const float*)d_in[0];   // [128, 4, 128] fp32
    const int*   labels = (const int*)d_in[1];     // [128] int32
    float* out = (float*)d_out;

    float*        psum = (float*)d_ws;               // NBLK floats
    float*        pcnt = psum + NBLK;                // NBLK floats
    unsigned int* flag = (unsigned int*)(pcnt + NBLK); // NBLK uints

    fused_all<<<NBLK, NT, 0, stream>>>(feat, labels, psum, pcnt, flag, out);
}

// Round 9
// 78.362 us; speedup vs baseline: 1.0031x; 1.0031x over previous
//
#include <hip/hip_runtime.h>
#include <math.h>

#define BB 128   // batch
#define VV 4     // views
#define NN 512   // BB*VV rows
#define DD 128   // feature dim
#define NT 256   // threads per block
#define NBLK 256 // blocks; 2 anchors per block (halves row-sweep traffic)

// ---------------------------------------------------------------------------
// Kernel 1: 256 blocks, 2 anchors per block (a0=bid, a1=bid+256).
// Phase 1: one fused sweep over all 512 rows computes ss_j and dot_j vs BOTH
//   anchors (8 lanes/row, 4 float4 loads/lane, butterfly reduce). Anchor
//   fragments in NAMED scalars — indexed arrays (R5) and cg::grid.sync (R6)
//   both demote registers to scratch (VGPR 32/24, 45-53 us kernels).
// Phase 2: per anchor: d_j = sqrt(max(sn_a+sn_j-2*dot*inv_a*inv_j,0))
//   (absmax 0.0 in rounds 2-8), ballot compaction into per-anchor pos/neg
//   LDS buffers, relu pair loops -> one partial per block.
// Two-launch structure: R7/R8 proved single-kernel flag-finalize costs ~7 us
// MORE than a graph-replayed second launch (coherent-point drain tail).
// Deterministic; no global atomics; ws write-before-read (no init needed).
// ---------------------------------------------------------------------------
__global__ __launch_bounds__(NT)
void fused_triplet(const float* __restrict__ feat,
                   const int* __restrict__ labels,
                   float* __restrict__ psum,
                   float* __restrict__ pcnt) {
    __shared__ float s_ss[NN];
    __shared__ float s_dot[2][NN];
    __shared__ float s_pos[2][NN];
    __shared__ float s_neg[2][NN];
    __shared__ int   s_lab[BB];
    __shared__ int   s_np[2], s_nn[2];
    __shared__ float s_wsum[NT / 64];
    __shared__ unsigned int s_wcnt[NT / 64];

    const int bid  = blockIdx.x;
    const int tid  = threadIdx.x;
    const int wave = tid >> 6;      // 0..3
    const int lane = tid & 63;
    const int grp  = lane >> 3;     // 8 row-groups of 8 lanes
    const int l8   = lane & 7;

    if (tid < BB) s_lab[tid] = labels[tid];
    if (tid == 0) { s_np[0] = 0; s_nn[0] = 0; s_np[1] = 0; s_nn[1] = 0; }

    // anchor fragments for both anchors — NAMED scalars (no spill)
    const int a0 = bid, a1 = bid + NBLK;
    const float4* ar0 = (const float4*)(feat + (size_t)(a0 & (BB - 1)) * (VV * DD) + (a0 >> 7) * DD);
    const float4* ar1 = (const float4*)(feat + (size_t)(a1 & (BB - 1)) * (VV * DD) + (a1 >> 7) * DD);
    float4 af0 = ar0[l8];
    float4 af1 = ar0[l8 + 8];
    float4 af2 = ar0[l8 + 16];
    float4 af3 = ar0[l8 + 24];
    float4 bf0 = ar1[l8];
    float4 bf1 = ar1[l8 + 8];
    float4 bf2 = ar1[l8 + 16];
    float4 bf3 = ar1[l8 + 24];

    // Phase 1: fused ss + dual-dot sweep; wave w covers rows [w*128, w*128+128)
    #pragma unroll 4
    for (int it = 0; it < 16; ++it) {
        const int j  = (wave << 7) + (it << 3) + grp;
        const int jb = j & (BB - 1), jv = j >> 7;
        const float4* jr = (const float4*)(feat + (size_t)jb * (VV * DD) + jv * DD);
        float4 x0 = jr[l8];
        float4 x1 = jr[l8 + 8];
        float4 x2 = jr[l8 + 16];
        float4 x3 = jr[l8 + 24];

        float ss = 0.f, d0 = 0.f, d1 = 0.f;
        ss = fmaf(x0.x, x0.x, fmaf(x0.y, x0.y, fmaf(x0.z, x0.z, fmaf(x0.w, x0.w, ss))));
        ss = fmaf(x1.x, x1.x, fmaf(x1.y, x1.y, fmaf(x1.z, x1.z, fmaf(x1.w, x1.w, ss))));
        ss = fmaf(x2.x, x2.x, fmaf(x2.y, x2.y, fmaf(x2.z, x2.z, fmaf(x2.w, x2.w, ss))));
        ss = fmaf(x3.x, x3.x, fmaf(x3.y, x3.y, fmaf(x3.z, x3.z, fmaf(x3.w, x3.w, ss))));
        d0 = fmaf(x0.x, af0.x, fmaf(x0.y, af0.y, fmaf(x0.z, af0.z, fmaf(x0.w, af0.w, d0))));
        d0 = fmaf(x1.x, af1.x, fmaf(x1.y, af1.y, fmaf(x1.z, af1.z, fmaf(x1.w, af1.w, d0))));
        d0 = fmaf(x2.x, af2.x, fmaf(x2.y, af2.y, fmaf(x2.z, af2.z, fmaf(x2.w, af2.w, d0))));
        d0 = fmaf(x3.x, af3.x, fmaf(x3.y, af3.y, fmaf(x3.z, af3.z, fmaf(x3.w, af3.w, d0))));
        d1 = fmaf(x0.x, bf0.x, fmaf(x0.y, bf0.y, fmaf(x0.z, bf0.z, fmaf(x0.w, bf0.w, d1))));
        d1 = fmaf(x1.x, bf1.x, fmaf(x1.y, bf1.y, fmaf(x1.z, bf1.z, fmaf(x1.w, bf1.w, d1))));
        d1 = fmaf(x2.x, bf2.x, fmaf(x2.y, bf2.y, fmaf(x2.z, bf2.z, fmaf(x2.w, bf2.w, d1))));
        d1 = fmaf(x3.x, bf3.x, fmaf(x3.y, bf3.y, fmaf(x3.z, bf3.z, fmaf(x3.w, bf3.w, d1))));

        #pragma unroll
        for (int off = 4; off > 0; off >>= 1) {
            ss += __shfl_xor(ss, off);
            d0 += __shfl_xor(d0, off);
            d1 += __shfl_xor(d1, off);
        }
        if (l8 == 0) { s_ss[j] = ss; s_dot[0][j] = d0; s_dot[1][j] = d1; }
    }
    __syncthreads();

    // Phase 2a+2b: per-anchor distances + compaction into per-anchor buffers
    #pragma unroll
    for (int h = 0; h < 2; ++h) {
        const int a = bid + (h << 8);
        const float ssa  = s_ss[a];
        const float inva = 1.f / fmaxf(sqrtf(ssa), 1e-12f);
        const float sna  = ssa * inva * inva;
        const int la = s_lab[a & (BB - 1)];
        #pragma unroll
        for (int rnd = 0; rnd < 2; ++rnd) {
            const int j = tid + (rnd << 8);
            float ssj  = s_ss[j];
            float invj = 1.f / fmaxf(sqrtf(ssj), 1e-12f);
            float snj  = ssj * invj * invj;
            float dot  = s_dot[h][j] * inva * invj;
            float sq   = fmaxf(sna + snj - 2.f * dot, 0.f);
            float dj   = (sq > 0.f) ? sqrtf(sq) : 0.f;   // safe_sqrt

            bool same  = (s_lab[j & (BB - 1)] == la);
            bool ispos = same & (j != a);
            bool isneg = !same;
            unsigned long long mp = __ballot(ispos);
            unsigned long long mn = __ballot(isneg);
            int basep = 0, basen = 0;
            if (lane == 0) {
                basep = atomicAdd(&s_np[h], (int)__popcll(mp));
                basen = atomicAdd(&s_nn[h], (int)__popcll(mn));
            }
            basep = __shfl(basep, 0);
            basen = __shfl(basen, 0);
            unsigned long long below = (1ull << lane) - 1ull;
            if (ispos) s_pos[h][basep + (int)__popcll(mp & below)] = dj;
            if (isneg) s_neg[h][basen + (int)__popcll(mn & below)] = dj;
        }
    }
    __syncthreads();

    // Phase 2c: pair loops for both anchors
    float lsum = 0.f;
    unsigned int lcnt = 0;
    #pragma unroll
    for (int h = 0; h < 2; ++h) {
        const int np = s_np[h], nneg = s_nn[h];
        for (int p = 0; p < np; ++p) {
            float dp = s_pos[h][p];              // LDS broadcast
            for (int n = tid; n < nneg; n += NT) {
                float diff = dp - s_neg[h][n];
                if (diff > 0.f) { lsum += diff; lcnt++; }
            }
        }
    }

    // Phase 3: block reduce -> one partial per block
    #pragma unroll
    for (int off = 32; off > 0; off >>= 1) {
        lsum += __shfl_down(lsum, off);
        lcnt += __shfl_down(lcnt, off);
    }
    if (lane == 0) { s_wsum[wave] = lsum; s_wcnt[wave] = lcnt; }
    __syncthreads();
    if (tid == 0) {
        psum[bid] = s_wsum[0] + s_wsum[1] + s_wsum[2] + s_wsum[3];
        pcnt[bid] = (float)(s_wcnt[0] + s_wcnt[1] + s_wcnt[2] + s_wcnt[3]);
    }
}

// ---------------------------------------------------------------------------
// Kernel 2: 256 partials -> scalar
// ---------------------------------------------------------------------------
__global__ __launch_bounds__(NT)
void reduce_final(const float* __restrict__ psum,
                  const float* __restrict__ pcnt,
                  float* __restrict__ out) {
    int tid = threadIdx.x;
    float s = psum[tid];
    float c = pcnt[tid];
    #pragma unroll
    for (int off = 32; off > 0; off >>= 1) {
        s += __shfl_down(s, off);
        c += __shfl_down(c, off);
    }
    __shared__ float ws[NT / 64], wc[NT / 64];
    if ((tid & 63) == 0) { ws[tid >> 6] = s; wc[tid >> 6] = c; }
    __syncthreads();
    if (tid == 0) {
        float S = ws[0] + ws[1] + ws[2] + ws[3];
        float C = wc[0] + wc[1] + wc[2] + wc[3];
        out[0] = (C > 0.f) ? S / C : 0.f;
    }
}

extern "C" void kernel_launch(void* const* d_in, const int* in_sizes, int n_in,
                              void* d_out, int out_size, void* d_ws, size_t ws_size,
                              hipStream_t stream) {
    const float* feat   = (const float*)d_in[0];   // [128, 4, 128] fp32
    const int*   labels = (const int*)d_in[1];     // [128] int32
    float* out = (float*)d_out;

    float* psum = (float*)d_ws;          // NBLK floats
    float* pcnt = psum + NBLK;           // NBLK floats

    fused_triplet<<<NBLK, NT, 0, stream>>>(feat, labels, psum, pcnt);
    reduce_final<<<1, NT, 0, stream>>>(psum, pcnt, out);
}